// Round 9
// baseline (154.541 us; speedup 1.0000x reference)
//
#include <hip/hip_runtime.h>

// DistributionLoss: local 7x7xC std (zero-padded) of two [16,3,512,512] fp32
// tensors, smooth-L1 mean between std maps -> scalar.
//
// R17: small-tile high-TLP variant of the R11/R16 pinned-burst design.
// R16 post-mortem: no spilling (WRITE=64KB; quads live in AGPRs), pipeline
// intact, yet HBM stuck at 2.3 TB/s with only ~2.3 blocks/CU co-resident
// -> the per-CU load-burst duty cycle is the wall (hypothesis a), or the
// L1/L2 request rate (4 instruction-touches per 64B line) is (hypothesis b).
// This round tests (a):
//  - TSY 32->16 (HR=22, LDS 22.5KB): 4096 blocks, 16 sequential blocks/CU.
//  - launch_bounds(256,5): VGPR cap 102, 5 blocks/CU = 20 waves (62% occ).
//  - Phase A: 1-deep pinned pipeline (12 quads = 48 VGPR live). Latency
//    hidden by TLP across 20 waves instead of per-wave pipeline depth.
//    Round 2 (tasks 256..351) only for tid<96: waves 2-3 skip uniformly,
//    wave 1 partially masked (masked lanes issue no requests; vmcnt is
//    per-wave instruction-consistent). No duplicated loads.
//  - Phase B: ONE row per thread (16 rows x 16 colgroups = 256, no idle
//    threads): 14 ds_read_b128 + std + fused smooth-L1.
// Math/masks/clamping identical to R16 (verified absmax 0).

typedef float f32x4 __attribute__((ext_vector_type(4)));

#define K     7
#define PAD   3
#define TSX   64
#define TSY   16
#define HR    (TSY + K - 1)   // 22 halo rows
#define LDSW  64              // LDS row stride (floats)
#define NT    256
#define HALF  (HR * 8)        // 176 tasks per input
#define NTASK (2 * HALF)      // 352 fused tasks (both inputs)

#define LOADQ(dst, ptr, OFF)                                        \
    asm volatile("global_load_dwordx4 %0, %1, off offset:" OFF      \
                 : "=v"(dst) : "v"(ptr))

#define WAITV(N) do {                                               \
    asm volatile("s_waitcnt vmcnt(" #N ")" ::: "memory");           \
    __builtin_amdgcn_sched_barrier(0);                              \
} while (0)

__global__ __launch_bounds__(NT, 5) void dist_loss_kernel(
    const float* __restrict__ pred,
    const float* __restrict__ tgt,
    float* __restrict__ out)
{
    constexpr int   C = 3, H = 512, W = 512;
    constexpr float INV_N     = 1.0f / (C * K * K);              // 1/147
    constexpr float INV_TOTAL = 1.0f / (16.0f * 512.0f * 512.0f);

    __shared__ float sh_s[2][HR][LDSW];   // horizontal 7-tap of channel sum
    __shared__ float sh_q[2][HR][LDSW];   // horizontal 7-tap of channel sum-sq

    const int    tid  = threadIdx.x;
    const int    tx0  = blockIdx.x * TSX;
    const int    ty0  = blockIdx.y * TSY;
    const int    b    = blockIdx.z;
    const size_t plane  = (size_t)H * W;
    const size_t planeB = plane * sizeof(float);

    const float* base0 = pred + (size_t)b * C * plane;
    const float* base1 = tgt  + (size_t)b * C * plane;

    float* shs = &sh_s[0][0][0];
    float* shq = &sh_q[0][0][0];

    // ---- Phase A: 1-deep pinned burst per round (12 quads live) ----
    #define DECL_SLOT(S)                                                     \
        const char *rB0_##S, *rB1_##S, *rB2_##S;                             \
        int cA_##S, cE_##S, idx_##S;                                         \
        float m_##S, mL_##S, mR_##S;                                         \
        f32x4 qA0_##S, qB0_##S, qD0_##S, qE0_##S,                            \
              qA1_##S, qB1_##S, qD1_##S, qE1_##S,                            \
              qA2_##S, qB2_##S, qD2_##S, qE2_##S;

    // decode task t; clamped (always-legal) addresses; garbage masked later
    #define SETUP(S, t) do {                                                 \
        const int which = ((t) >= HALF) ? 1 : 0;                             \
        const int tt    = (t) - which * HALF;                                \
        const int row   = tt >> 3, cg = tt & 7;                              \
        const int gy    = ty0 - PAD + row;                                   \
        m_##S  = ((unsigned)gy < (unsigned)H) ? 1.f : 0.f;                   \
        const int gyc = min(max(gy, 0), H - 1);                              \
        const int gx0 = tx0 + (cg << 3);                                     \
        mL_##S = (gx0 > 0)   ? 1.f : 0.f;                                    \
        mR_##S = (gx0 < 504) ? 1.f : 0.f;                                    \
        const float* base = which ? base1 : base0;                           \
        rB0_##S = (const char*)(base + (size_t)gyc * W + gx0);               \
        rB1_##S = rB0_##S + planeB;                                          \
        rB2_##S = rB1_##S + planeB;                                          \
        cA_##S  = (gx0 > 0)   ? -16 : 0;                                     \
        cE_##S  = (gx0 < 504) ?  32 : 16;                                    \
        idx_##S = (which * HR + row) * LDSW + (cg << 3);                     \
    } while (0)

    #define ISSUE(S) do {                                                    \
        LOADQ(qA0_##S, rB0_##S + cA_##S, "0");                               \
        LOADQ(qB0_##S, rB0_##S,          "0");                               \
        LOADQ(qD0_##S, rB0_##S,          "16");                              \
        LOADQ(qE0_##S, rB0_##S + cE_##S, "0");                               \
        LOADQ(qA1_##S, rB1_##S + cA_##S, "0");                               \
        LOADQ(qB1_##S, rB1_##S,          "0");                               \
        LOADQ(qD1_##S, rB1_##S,          "16");                              \
        LOADQ(qE1_##S, rB1_##S + cE_##S, "0");                               \
        LOADQ(qA2_##S, rB2_##S + cA_##S, "0");                               \
        LOADQ(qB2_##S, rB2_##S,          "0");                               \
        LOADQ(qD2_##S, rB2_##S,          "16");                              \
        LOADQ(qE2_##S, rB2_##S + cE_##S, "0");                               \
    } while (0)

    #define CONSUME(S) do {                                                  \
        f32x4 tl = qA0_##S + qA1_##S + qA2_##S;                              \
        f32x4 ta = qB0_##S + qB1_##S + qB2_##S;                              \
        f32x4 tb = qD0_##S + qD1_##S + qD2_##S;                              \
        f32x4 tr = qE0_##S + qE1_##S + qE2_##S;                              \
        f32x4 ul = qA0_##S*qA0_##S + qA1_##S*qA1_##S + qA2_##S*qA2_##S;      \
        f32x4 ua = qB0_##S*qB0_##S + qB1_##S*qB1_##S + qB2_##S*qB2_##S;      \
        f32x4 ub = qD0_##S*qD0_##S + qD1_##S*qD1_##S + qD2_##S*qD2_##S;      \
        f32x4 ur = qE0_##S*qE0_##S + qE1_##S*qE1_##S + qE2_##S*qE2_##S;      \
        tl[1] *= mL_##S; tl[2] *= mL_##S; tl[3] *= mL_##S;                   \
        ul[1] *= mL_##S; ul[2] *= mL_##S; ul[3] *= mL_##S;                   \
        tr[0] *= mR_##S; tr[1] *= mR_##S; tr[2] *= mR_##S;                   \
        ur[0] *= mR_##S; ur[1] *= mR_##S; ur[2] *= mR_##S;                   \
        float h0 = tl[1]+tl[2]+tl[3]+ta[0]+ta[1]+ta[2]+ta[3];                \
        float h1 = h0 - tl[1] + tb[0];                                       \
        float h2 = h1 - tl[2] + tb[1];                                       \
        float h3 = h2 - tl[3] + tb[2];                                       \
        float h4 = h3 - ta[0] + tb[3];                                       \
        float h5 = h4 - ta[1] + tr[0];                                       \
        float h6 = h5 - ta[2] + tr[1];                                       \
        float h7 = h6 - ta[3] + tr[2];                                       \
        float g0 = ul[1]+ul[2]+ul[3]+ua[0]+ua[1]+ua[2]+ua[3];                \
        float g1 = g0 - ul[1] + ub[0];                                       \
        float g2 = g1 - ul[2] + ub[1];                                       \
        float g3 = g2 - ul[3] + ub[2];                                       \
        float g4 = g3 - ua[0] + ub[3];                                       \
        float g5 = g4 - ua[1] + ur[0];                                       \
        float g6 = g5 - ua[2] + ur[1];                                       \
        float g7 = g6 - ua[3] + ur[2];                                       \
        const float mm = m_##S;                                              \
        *(f32x4*)&shs[idx_##S]     = (f32x4){h0*mm, h1*mm, h2*mm, h3*mm};    \
        *(f32x4*)&shs[idx_##S + 4] = (f32x4){h4*mm, h5*mm, h6*mm, h7*mm};    \
        *(f32x4*)&shq[idx_##S]     = (f32x4){g0*mm, g1*mm, g2*mm, g3*mm};    \
        *(f32x4*)&shq[idx_##S + 4] = (f32x4){g4*mm, g5*mm, g6*mm, g7*mm};    \
    } while (0)

    DECL_SLOT(0);

    // round 0: tasks 0..255 (all threads)
    SETUP(0, tid); ISSUE(0);
    WAITV(0);
    CONSUME(0);
    // round 1: tasks 256..351 (tid<96 only; waves 2-3 skip uniformly,
    // wave 1 partially masked — vmcnt stays per-wave consistent)
    if (tid < NTASK - NT) {
        SETUP(0, tid + NT); ISSUE(0);
        WAITV(0);
        CONSUME(0);
    }

    __syncthreads();

    // ---- Phase B: vertical 7-tap + std + fused smooth-L1; 1 row/thread
    float acc = 0.0f;
    {
        const int r = tid >> 4;           // output row 0..15
        const int x = (tid & 15) << 2;    // col within tile

        f32x4 pA;                         // input 0 std quad

        #define STD4(Sv, Qv, D) do {                                         \
            _Pragma("unroll")                                                \
            for (int c_ = 0; c_ < 4; ++c_) {                                 \
                float mu_ = (Sv)[c_] * INV_N;                                \
                (D)[c_] = sqrtf(fmaf(-mu_, mu_, (Qv)[c_] * INV_N) + 1e-8f);  \
            }                                                                \
        } while (0)
        #define SL1(a, bb) do {                                              \
            float d_  = (a) - (bb);                                          \
            float ad_ = fabsf(d_);                                           \
            acc += (ad_ < 1.0f) ? 0.5f * d_ * d_ : (ad_ - 0.5f);             \
        } while (0)

        #pragma unroll
        for (int w = 0; w < 2; ++w) {
            f32x4 S = (f32x4){0.f, 0.f, 0.f, 0.f};
            f32x4 Q = (f32x4){0.f, 0.f, 0.f, 0.f};
            #pragma unroll
            for (int k = 0; k < K; ++k) {
                S += *(const f32x4*)&sh_s[w][r + k][x];
                Q += *(const f32x4*)&sh_q[w][r + k][x];
            }
            if (w == 0) {
                STD4(S, Q, pA);
            } else {
                f32x4 sA;
                STD4(S, Q, sA);
                SL1(pA[0], sA[0]); SL1(pA[1], sA[1]);
                SL1(pA[2], sA[2]); SL1(pA[3], sA[3]);
            }
        }
        #undef STD4
        #undef SL1
    }

    // ---- block reduction: wave64 shuffle, cross-wave via LDS, one atomic
    #pragma unroll
    for (int off = 32; off > 0; off >>= 1)
        acc += __shfl_down(acc, off, 64);

    __shared__ float wave_sums[NT / 64];
    if ((tid & 63) == 0) wave_sums[tid >> 6] = acc;
    __syncthreads();
    if (tid == 0) {
        float s = 0.0f;
        #pragma unroll
        for (int w = 0; w < NT / 64; ++w) s += wave_sums[w];
        atomicAdd(out, s * INV_TOTAL);
    }
}

extern "C" void kernel_launch(void* const* d_in, const int* in_sizes, int n_in,
                              void* d_out, int out_size, void* d_ws, size_t ws_size,
                              hipStream_t stream) {
    const float* pred = (const float*)d_in[0];
    const float* tgt  = (const float*)d_in[1];
    float* out = (float*)d_out;

    hipMemsetAsync(out, 0, sizeof(float), stream);

    dim3 grid(512 / TSX, 512 / TSY, 16);   // 8 x 32 x 16 = 4096 blocks
    dist_loss_kernel<<<grid, NT, 0, stream>>>(pred, tgt, out);
}

// Round 11
// 135.616 us; speedup vs baseline: 1.1395x; 1.1395x over previous
//
#include <hip/hip_runtime.h>

// DistributionLoss: local 7x7xC std (zero-padded) of two [16,3,512,512] fp32
// tensors, smooth-L1 mean between std maps -> scalar.
//
// R19: R18 (copy-shaped streaming: half-split inputs, shuffle horizontal,
// register-ring vertical, zero LDS / zero barriers) with the two R18 bugs
// fixed:
//  1. FULL UNROLL of the 38-row loop. R18's partial unroll carried
//     in-flight asm-output registers across a loop back edge; PHI-resolving
//     v_mov copies execute before the pending load retires -> stale garbage
//     -> NaN. All passing pinned-asm kernels (R11/R16/R17) were straight-
//     line; this restores that regime (every ring index / slot parity /
//     vmcnt literal is compile-time).
//  2. Masked accumulate is a SELECT (vok ? sl : 0), not *mask: halo lanes
//     (cross-half shuffle contamination, lanes lp=0/31) can hold garbage;
//     NaN*0 = NaN leaked into the reduction.
// Shape per iteration: 3 pinned global_load_dwordx4 (1KB contiguous per
// half-wave each; 3ch x 2 inputs via lane-half split), channel reduce,
// 12 lane shuffles for the horizontal 7-tap, 8-slot register ring vertical
// 7-tap, std + smooth-L1 via shfl_xor(32). Depth-2 pipeline: WAITV(3)
// steady, WAITV(0) drain. Strips: 120 valid cols x 32 rows; grid 5x16x16.

typedef float f32x4 __attribute__((ext_vector_type(4)));

#define SH     32
#define NROW   (SH + 6)          // 38 input rows per strip
#define NT     64
#define NSTRIP 5                 // x-strips of 120 output cols

#define LOADQ(dst, ptr)                                             \
    asm volatile("global_load_dwordx4 %0, %1, off"                  \
                 : "=v"(dst) : "v"(ptr))

#define WAITV(N) do {                                               \
    asm volatile("s_waitcnt vmcnt(" #N ")" ::: "memory");           \
    __builtin_amdgcn_sched_barrier(0);                              \
} while (0)

__global__ __launch_bounds__(NT, 2) void dist_loss_kernel(
    const float* __restrict__ pred,
    const float* __restrict__ tgt,
    float* __restrict__ out)
{
    constexpr int   W = 512, H = 512;
    constexpr float INV_N   = 1.0f / 147.0f;
    constexpr float INV_TOT = 0.5f / (16.0f * 512.0f * 512.0f);  // x0.5: halves duplicate

    const int l   = threadIdx.x;
    const int lp  = l & 31;          // lane within half
    const int inp = l >> 5;          // 0: pred, 1: tgt
    const int x0  = blockIdx.x * 120;
    const int ys  = blockIdx.y * SH;
    const int b   = blockIdx.z;

    const size_t plane  = (size_t)H * W;
    const size_t planeB = plane * 4;

    const int c0  = x0 - 4 + (lp << 2);              // t-col base of this lane
    const int c0c = min(max(c0, 0), W - 4);          // clamped, 16B-aligned

    const char* base0 =
        (const char*)((inp ? tgt : pred) + (size_t)b * 3 * plane + c0c);

    f32x4 mcol;
    bool  vok[4];
    #pragma unroll
    for (int j = 0; j < 4; ++j) {
        const int c = c0 + j;
        mcol[j] = (c >= 0 && c < W) ? 1.f : 0.f;                  // zero-pad cols
        vok[j]  = (lp >= 1 && lp <= 30 && c < W);                 // valid output
    }

    // vertical 7-tap ring: 8 static slots (indices constant after unroll)
    f32x4 z4 = (f32x4){0.f, 0.f, 0.f, 0.f};
    f32x4 rH[8], rG[8];
    #pragma unroll
    for (int r = 0; r < 8; ++r) { rH[r] = z4; rG[r] = z4; }
    f32x4 Sr = z4, Qr = z4;
    float acc = 0.f;

    // pipeline slots: [parity][channel] quads
    f32x4 q[2][3];

    #define ISSUE(P_, i_) do {                                               \
        const int gyc_ = min(max(ys - 3 + (i_), 0), H - 1);                  \
        const char* a_ = base0 + (size_t)gyc_ * (W * 4);                     \
        LOADQ(q[P_][0], a_);                                                 \
        LOADQ(q[P_][1], a_ + planeB);                                        \
        LOADQ(q[P_][2], a_ + 2 * planeB);                                    \
    } while (0)

    #define CONS(P_, i_) do {                                                \
        const int   gy_ = ys - 3 + (i_);                                     \
        const float rm_ = ((unsigned)gy_ < (unsigned)H) ? 1.f : 0.f;         \
        f32x4 mc_ = mcol * rm_;                                              \
        f32x4 t_ = (q[P_][0] + q[P_][1] + q[P_][2]) * mc_;                   \
        f32x4 u_ = (q[P_][0]*q[P_][0] + q[P_][1]*q[P_][1]                    \
                    + q[P_][2]*q[P_][2]) * mc_;                              \
        float tl1 = __shfl_up(t_[1], 1);                                     \
        float tl2 = __shfl_up(t_[2], 1);                                     \
        float tl3 = __shfl_up(t_[3], 1);                                     \
        float tr0 = __shfl_down(t_[0], 1);                                   \
        float tr1 = __shfl_down(t_[1], 1);                                   \
        float tr2 = __shfl_down(t_[2], 1);                                   \
        float ul1 = __shfl_up(u_[1], 1);                                     \
        float ul2 = __shfl_up(u_[2], 1);                                     \
        float ul3 = __shfl_up(u_[3], 1);                                     \
        float ur0 = __shfl_down(u_[0], 1);                                   \
        float ur1 = __shfl_down(u_[1], 1);                                   \
        float ur2 = __shfl_down(u_[2], 1);                                   \
        f32x4 h_, g_;                                                        \
        h_[0] = tl1 + tl2 + tl3 + t_[0] + t_[1] + t_[2] + t_[3];             \
        h_[1] = h_[0] - tl1 + tr0;                                           \
        h_[2] = h_[1] - tl2 + tr1;                                           \
        h_[3] = h_[2] - tl3 + tr2;                                           \
        g_[0] = ul1 + ul2 + ul3 + u_[0] + u_[1] + u_[2] + u_[3];             \
        g_[1] = g_[0] - ul1 + ur0;                                           \
        g_[2] = g_[1] - ul2 + ur1;                                           \
        g_[3] = g_[2] - ul3 + ur2;                                           \
        Sr += h_ - rH[((i_) + 1) & 7]; rH[(i_) & 7] = h_;                    \
        Qr += g_ - rG[((i_) + 1) & 7]; rG[(i_) & 7] = g_;                    \
        if ((i_) >= 6) {                                                     \
            f32x4 sd_;                                                       \
            _Pragma("unroll")                                                \
            for (int j_ = 0; j_ < 4; ++j_) {                                 \
                float mu_ = Sr[j_] * INV_N;                                  \
                sd_[j_] = sqrtf(fmaf(-mu_, mu_, Qr[j_] * INV_N) + 1e-8f);    \
            }                                                                \
            _Pragma("unroll")                                                \
            for (int j_ = 0; j_ < 4; ++j_) {                                 \
                float o_  = __shfl_xor(sd_[j_], 32);                         \
                float d_  = sd_[j_] - o_;                                    \
                float ad_ = fabsf(d_);                                       \
                float sl_ = (ad_ < 1.f) ? 0.5f * d_ * d_ : (ad_ - 0.5f);     \
                acc += vok[j_] ? sl_ : 0.0f;   /* select: no NaN leak */     \
            }                                                                \
        }                                                                    \
    } while (0)

    ISSUE(0, 0);
    ISSUE(1, 1);

    // FULL unroll: straight-line — no loop-carried in-flight asm outputs,
    // all ring indices / parities / vmcnt literals compile-time.
    #pragma unroll
    for (int i = 0; i < NROW; ++i) {
        if (i < NROW - 2) WAITV(3); else WAITV(0);
        CONS(i & 1, i);
        if (i + 2 < NROW) ISSUE(i & 1, i + 2);
    }

    #undef CONS
    #undef ISSUE

    // wave reduction + one atomic per block
    #pragma unroll
    for (int off = 32; off > 0; off >>= 1)
        acc += __shfl_down(acc, off, 64);
    if (l == 0) atomicAdd(out, acc * INV_TOT);
}

extern "C" void kernel_launch(void* const* d_in, const int* in_sizes, int n_in,
                              void* d_out, int out_size, void* d_ws, size_t ws_size,
                              hipStream_t stream) {
    const float* pred = (const float*)d_in[0];
    const float* tgt  = (const float*)d_in[1];
    float* out = (float*)d_out;

    hipMemsetAsync(out, 0, sizeof(float), stream);

    dim3 grid(NSTRIP, 512 / SH, 16);   // 5 x 16 x 16 = 1280 one-wave blocks
    dist_loss_kernel<<<grid, NT, 0, stream>>>(pred, tgt, out);
}